// Round 4
// baseline (441.496 us; speedup 1.0000x reference)
//
#include <hip/hip_runtime.h>

#define N_I 500000
#define N_H 200000
#define E1  2000000
#define E2  2000000
#define TOTAL_E (E1 + E2)

#define CHUNK 2048                  // edges per workgroup
#define NWG ((TOTAL_E + CHUNK - 1) / CHUNK)   // = 1954
#define ITERS (CHUNK / 256)         // 8 edges per thread

#define NBI_BLK ((N_I + 255) / 256) // 1954
#define NBH_BLK ((N_H + 255) / 256) // 782

typedef float f4 __attribute__((ext_vector_type(4)));   // nontemporal-compatible

// ---------------------------------------------------------------------------
// Per-node precompute, fp16 split layout:
//   g8[n] = uint4 holding 8 x fp16 of x[n]^T @ W_edge   (16 B, gathered)
//   gc[n] = fp16 dot(x[n], b_edge)                      (2 B, L2-resident)
// ROOT: out[n] = dot(x[n], Wr1+Wr2) + rb1 + rb2  (fp32, exact).
// Both node types handled by one launch (blockIdx partition).
// ---------------------------------------------------------------------------
template<int F, bool ROOT>
__device__ __forceinline__ void precompute_body(
    int blk, int tid,
    const float* __restrict__ x, const float* __restrict__ W, const float* __restrict__ b,
    uint4* __restrict__ g8, _Float16* __restrict__ gc, int n,
    const float* __restrict__ rW1, const float* __restrict__ rW2,
    const float* __restrict__ rb1, const float* __restrict__ rb2,
    float* __restrict__ out,
    float* Wf, float* bv, float* wr)
{
    for (int i = tid; i < F * 8; i += 256) Wf[i] = W[i];
    if (tid < F) {
        bv[tid] = b[tid];
        if (ROOT) wr[tid] = rW1[tid] + rW2[tid];
    }
    __syncthreads();

    int nid = blk * 256 + tid;
    if (nid >= n) return;

    float xv[F];
    const f4* xp = (const f4*)(x + (size_t)nid * F);
    #pragma unroll
    for (int q = 0; q < F / 4; q++) {
        f4 v = __builtin_nontemporal_load(xp + q);
        xv[q*4+0] = v[0]; xv[q*4+1] = v[1]; xv[q*4+2] = v[2]; xv[q*4+3] = v[3];
    }

    float acc[9];
    #pragma unroll
    for (int k = 0; k < 9; k++) acc[k] = 0.f;

    #pragma unroll
    for (int j = 0; j < F; j++) {
        float4 w0 = *(const float4*)(Wf + j * 8);
        float4 w1 = *(const float4*)(Wf + j * 8 + 4);
        float xj = xv[j];
        acc[0] = fmaf(xj, w0.x, acc[0]);
        acc[1] = fmaf(xj, w0.y, acc[1]);
        acc[2] = fmaf(xj, w0.z, acc[2]);
        acc[3] = fmaf(xj, w0.w, acc[3]);
        acc[4] = fmaf(xj, w1.x, acc[4]);
        acc[5] = fmaf(xj, w1.y, acc[5]);
        acc[6] = fmaf(xj, w1.z, acc[6]);
        acc[7] = fmaf(xj, w1.w, acc[7]);
        acc[8] = fmaf(xj, bv[j], acc[8]);
    }

    union { _Float16 h[8]; uint4 u; } pk;
    #pragma unroll
    for (int k = 0; k < 8; k++) pk.h[k] = (_Float16)acc[k];
    g8[nid] = pk.u;
    gc[nid] = (_Float16)acc[8];

    if (ROOT) {
        float r = rb1[0] + rb2[0];
        #pragma unroll
        for (int j = 0; j < F; j++) r = fmaf(xv[j], wr[j], r);
        out[nid] = r;
    }
}

__global__ __launch_bounds__(256) void precompute_both(
    const float* __restrict__ x_i, const float* __restrict__ We_i, const float* __restrict__ be_i,
    uint4* __restrict__ g8_i, _Float16* __restrict__ gc_i,
    const float* __restrict__ x_h, const float* __restrict__ We_h, const float* __restrict__ be_h,
    uint4* __restrict__ g8_h, _Float16* __restrict__ gc_h,
    const float* __restrict__ rW1, const float* __restrict__ rW2,
    const float* __restrict__ rb1, const float* __restrict__ rb2,
    float* __restrict__ out)
{
    __shared__ float Wf[32 * 8];
    __shared__ float bv[32];
    __shared__ float wr[32];

    if (blockIdx.x < NBI_BLK) {
        precompute_body<32, true>(blockIdx.x, threadIdx.x, x_i, We_i, be_i,
                                  g8_i, gc_i, N_I, rW1, rW2, rb1, rb2, out, Wf, bv, wr);
    } else {
        precompute_body<16, false>(blockIdx.x - NBI_BLK, threadIdx.x, x_h, We_h, be_h,
                                   g8_h, gc_h, N_H, nullptr, nullptr, nullptr, nullptr,
                                   nullptr, Wf, bv, wr);
    }
}

// ---------------------------------------------------------------------------
// Per-edge message: msg = dot(fp16 g8[src], fp32 ea[e]) + gc[src].
// ---------------------------------------------------------------------------
__device__ __forceinline__ float msg_dot(uint4 gu, f4 a0, f4 a1, float base) {
    union { uint4 u; _Float16 h[8]; } pk; pk.u = gu;
    float m = base;
    m = fmaf((float)pk.h[0], a0[0], m);
    m = fmaf((float)pk.h[1], a0[1], m);
    m = fmaf((float)pk.h[2], a0[2], m);
    m = fmaf((float)pk.h[3], a0[3], m);
    m = fmaf((float)pk.h[4], a1[0], m);
    m = fmaf((float)pk.h[5], a1[1], m);
    m = fmaf((float)pk.h[6], a1[2], m);
    m = fmaf((float)pk.h[7], a1[3], m);
    return m;
}

__device__ __forceinline__ void compute_msgs8(
    int tid, int ebase,
    const int* __restrict__ src, const int* __restrict__ dst,
    const float* __restrict__ ea, const uint4* __restrict__ g8,
    const _Float16* __restrict__ gc,
    int* dloc, float* mloc)
{
    int sl[ITERS];
    #pragma unroll
    for (int it = 0; it < ITERS; ++it) {
        int e = ebase + it * 256 + tid;
        sl[it] = __builtin_nontemporal_load(&src[e]);
        dloc[it] = __builtin_nontemporal_load(&dst[e]);
    }
    #pragma unroll
    for (int h = 0; h < 2; ++h) {
        uint4 g[4]; f4 a0[4], a1[4];
        float gv[4];
        #pragma unroll
        for (int k = 0; k < 4; ++k) {
            int it = h * 4 + k;
            int e = ebase + it * 256 + tid;
            int s = sl[it];
            g[k] = g8[s];
            gv[k] = (float)gc[s];
            const f4* ap = (const f4*)(ea + (size_t)e * 8);
            a0[k] = __builtin_nontemporal_load(ap);
            a1[k] = __builtin_nontemporal_load(ap + 1);
        }
        #pragma unroll
        for (int k = 0; k < 4; ++k)
            mloc[h * 4 + k] = msg_dot(g[k], a0[k], a1[k], gv[k]);
    }
}

// ---------------------------------------------------------------------------
// Fused edge kernel: msg compute + direct atomicAdd into out (2 MB,
// L2-resident; ~8 edges/node average -> negligible contention).
// No barriers, no LDS -> streams at full latency-hidden BW.
// ---------------------------------------------------------------------------
__global__ __launch_bounds__(256) void edge_atomic_kernel(
    const int* __restrict__ src1, const int* __restrict__ dst1,
    const float* __restrict__ ea1, const uint4* __restrict__ g8_1, const _Float16* __restrict__ gc_1,
    const int* __restrict__ src2, const int* __restrict__ dst2,
    const float* __restrict__ ea2, const uint4* __restrict__ g8_2, const _Float16* __restrict__ gc_2,
    float* __restrict__ out)
{
    int tid = threadIdx.x;
    int cbase = blockIdx.x * CHUNK;
    int dloc[ITERS];
    float mloc[ITERS];

    if (cbase + CHUNK <= E1) {
        compute_msgs8(tid, cbase, src1, dst1, ea1, g8_1, gc_1, dloc, mloc);
    } else if (cbase >= E1 && cbase + CHUNK <= TOTAL_E) {
        compute_msgs8(tid, cbase - E1, src2, dst2, ea2, g8_2, gc_2, dloc, mloc);
    } else {
        // straddling (WG 976) or partial-tail (WG 1953) chunk: generic path
        #pragma unroll
        for (int it = 0; it < ITERS; ++it) {
            int t = cbase + it * 256 + tid;
            int d = -1; float m = 0.f;
            if (t < TOTAL_E) {
                const int* srcp; const int* dstp; const float* eap;
                const uint4* g8p; const _Float16* gcp; int e;
                if (t < E1) { e = t;      srcp = src1; dstp = dst1; eap = ea1; g8p = g8_1; gcp = gc_1; }
                else        { e = t - E1; srcp = src2; dstp = dst2; eap = ea2; g8p = g8_2; gcp = gc_2; }
                int s = srcp[e];
                d = dstp[e];
                uint4 gu = g8p[s];
                const f4* ap = (const f4*)(eap + (size_t)e * 8);
                f4 a0 = ap[0];
                f4 a1 = ap[1];
                m = msg_dot(gu, a0, a1, (float)gcp[s]);
            }
            dloc[it] = d; mloc[it] = m;
        }
    }

    #pragma unroll
    for (int it = 0; it < ITERS; ++it)
        if (dloc[it] >= 0) atomicAdd(out + dloc[it], mloc[it]);
}

extern "C" void kernel_launch(void* const* d_in, const int* in_sizes, int n_in,
                              void* d_out, int out_size, void* d_ws, size_t ws_size,
                              hipStream_t stream) {
    const float* x_i  = (const float*)d_in[0];
    const float* x_h  = (const float*)d_in[1];
    const float* ea_h = (const float*)d_in[2];
    const float* ea_i = (const float*)d_in[3];
    const float* We_h = (const float*)d_in[4];
    const float* be_h = (const float*)d_in[5];
    const float* We_i = (const float*)d_in[6];
    const float* be_i = (const float*)d_in[7];
    const float* Wr_h = (const float*)d_in[8];
    const float* br_h = (const float*)d_in[9];
    const float* Wr_i = (const float*)d_in[10];
    const float* br_i = (const float*)d_in[11];
    const int* src_h = (const int*)d_in[12];
    const int* dst_h = (const int*)d_in[13];
    const int* src_i = (const int*)d_in[14];
    const int* dst_i = (const int*)d_in[15];

    float* out = (float*)d_out;

    // workspace layout (~12.6 MB total):
    //   g8_i [0, 8.0 MB) fp16x8 records (gathered)
    //   g8_h [8.0, 11.2 MB)
    //   gc_i [11.2, 12.2 MB) fp16 (L2-resident)
    //   gc_h [12.2, 12.6 MB)
    char* ws = (char*)d_ws;
    uint4*    g8_i = (uint4*)ws;                            //  8,000,000 B
    uint4*    g8_h = (uint4*)(ws + 8000000);                //  3,200,000 B
    _Float16* gc_i = (_Float16*)(ws + 11200000);            //  1,000,000 B
    _Float16* gc_h = (_Float16*)(ws + 12200000);            //    400,000 B

    // precompute g8/gc for both node types + root term into out (one launch)
    precompute_both<<<NBI_BLK + NBH_BLK, 256, 0, stream>>>(
        x_i, We_i, be_i, g8_i, gc_i,
        x_h, We_h, be_h, g8_h, gc_h,
        Wr_h, Wr_i, br_h, br_i, out);

    // fused message + aggregation (direct atomics into 2 MB L2-resident out)
    edge_atomic_kernel<<<NWG, 256, 0, stream>>>(
        src_h, dst_h, ea_h, g8_h, gc_h,
        src_i, dst_i, ea_i, g8_i, gc_i, out);
}

// Round 5
// 365.230 us; speedup vs baseline: 1.2088x; 1.2088x over previous
//
#include <hip/hip_runtime.h>

#define N_I 500000
#define N_H 200000
#define E1  2000000
#define E2  2000000
#define TOTAL_E (E1 + E2)

#define BSHIFT 12                   // bucket = dst >> 12 (4096 nodes/bucket)
#define NB 128                      // allocated buckets; 123 used
#define NBK ((N_I + 4095) / 4096)   // = 123 used buckets
#define CHUNK 2048                  // edges per workgroup (hist/scatter)
#define NWG ((TOTAL_E + CHUNK - 1) / CHUNK)   // = 1954
#define WPT 8                       // H entries per thread in scan_cols
#define ITERS (CHUNK / 256)         // 8 edges per thread

#define NBI_BLK ((N_I + 255) / 256) // 1954
#define NBH_BLK ((N_H + 255) / 256) // 782

typedef float f4 __attribute__((ext_vector_type(4)));   // nontemporal-compatible

// ---------------------------------------------------------------------------
// Per-node precompute, fp16 split layout (one launch for both node types):
//   g8[n] = uint4 holding 8 x fp16 of x[n]^T @ W_edge   (16 B, gathered)
//   gc[n] = fp16 dot(x[n], b_edge)                      (2 B, L2-resident)
// ROOT: out[n] = dot(x[n], Wr1+Wr2) + rb1 + rb2  (fp32, exact).
// ---------------------------------------------------------------------------
template<int F, bool ROOT>
__device__ __forceinline__ void precompute_body(
    int blk, int tid,
    const float* __restrict__ x, const float* __restrict__ W, const float* __restrict__ b,
    uint4* __restrict__ g8, _Float16* __restrict__ gc, int n,
    const float* __restrict__ rW1, const float* __restrict__ rW2,
    const float* __restrict__ rb1, const float* __restrict__ rb2,
    float* __restrict__ out,
    float* Wf, float* bv, float* wr)
{
    for (int i = tid; i < F * 8; i += 256) Wf[i] = W[i];
    if (tid < F) {
        bv[tid] = b[tid];
        if (ROOT) wr[tid] = rW1[tid] + rW2[tid];
    }
    __syncthreads();

    int nid = blk * 256 + tid;
    if (nid >= n) return;

    float xv[F];
    const f4* xp = (const f4*)(x + (size_t)nid * F);
    #pragma unroll
    for (int q = 0; q < F / 4; q++) {
        f4 v = __builtin_nontemporal_load(xp + q);
        xv[q*4+0] = v[0]; xv[q*4+1] = v[1]; xv[q*4+2] = v[2]; xv[q*4+3] = v[3];
    }

    float acc[9];
    #pragma unroll
    for (int k = 0; k < 9; k++) acc[k] = 0.f;

    #pragma unroll
    for (int j = 0; j < F; j++) {
        float4 w0 = *(const float4*)(Wf + j * 8);
        float4 w1 = *(const float4*)(Wf + j * 8 + 4);
        float xj = xv[j];
        acc[0] = fmaf(xj, w0.x, acc[0]);
        acc[1] = fmaf(xj, w0.y, acc[1]);
        acc[2] = fmaf(xj, w0.z, acc[2]);
        acc[3] = fmaf(xj, w0.w, acc[3]);
        acc[4] = fmaf(xj, w1.x, acc[4]);
        acc[5] = fmaf(xj, w1.y, acc[5]);
        acc[6] = fmaf(xj, w1.z, acc[6]);
        acc[7] = fmaf(xj, w1.w, acc[7]);
        acc[8] = fmaf(xj, bv[j], acc[8]);
    }

    union { _Float16 h[8]; uint4 u; } pk;
    #pragma unroll
    for (int k = 0; k < 8; k++) pk.h[k] = (_Float16)acc[k];
    g8[nid] = pk.u;
    gc[nid] = (_Float16)acc[8];

    if (ROOT) {
        float r = rb1[0] + rb2[0];
        #pragma unroll
        for (int j = 0; j < F; j++) r = fmaf(xv[j], wr[j], r);
        out[nid] = r;
    }
}

__global__ __launch_bounds__(256) void precompute_both(
    const float* __restrict__ x_i, const float* __restrict__ We_i, const float* __restrict__ be_i,
    uint4* __restrict__ g8_i, _Float16* __restrict__ gc_i,
    const float* __restrict__ x_h, const float* __restrict__ We_h, const float* __restrict__ be_h,
    uint4* __restrict__ g8_h, _Float16* __restrict__ gc_h,
    const float* __restrict__ rW1, const float* __restrict__ rW2,
    const float* __restrict__ rb1, const float* __restrict__ rb2,
    float* __restrict__ out)
{
    __shared__ float Wf[32 * 8];
    __shared__ float bv[32];
    __shared__ float wr[32];

    if (blockIdx.x < NBI_BLK) {
        precompute_body<32, true>(blockIdx.x, threadIdx.x, x_i, We_i, be_i,
                                  g8_i, gc_i, N_I, rW1, rW2, rb1, rb2, out, Wf, bv, wr);
    } else {
        precompute_body<16, false>(blockIdx.x - NBI_BLK, threadIdx.x, x_h, We_h, be_h,
                                   g8_h, gc_h, N_H, nullptr, nullptr, nullptr, nullptr,
                                   nullptr, Wf, bv, wr);
    }
}

// ---------------------------------------------------------------------------
// Kernel A: dst-only histogram (16 MB streaming read).
// ---------------------------------------------------------------------------
__global__ __launch_bounds__(256) void hist_kernel(
    const int* __restrict__ dst1, const int* __restrict__ dst2,
    int* __restrict__ H)
{
    __shared__ int hist[NB];
    if (threadIdx.x < NB) hist[threadIdx.x] = 0;
    __syncthreads();

    int base = blockIdx.x * CHUNK;
    #pragma unroll
    for (int it = 0; it < ITERS; ++it) {
        int t = base + it * 256 + threadIdx.x;
        if (t < TOTAL_E) {
            int d = (t < E1) ? __builtin_nontemporal_load(&dst1[t])
                             : __builtin_nontemporal_load(&dst2[t - E1]);
            atomicAdd(&hist[d >> BSHIFT], 1);
        }
    }
    __syncthreads();
    if (threadIdx.x < NB) H[blockIdx.x * NB + threadIdx.x] = hist[threadIdx.x];
}

// Kernel B: per bucket b, exclusive scan of H[w][b] over w, in place.
__global__ __launch_bounds__(256) void scan_cols_kernel(int* __restrict__ H,
                                                        int* __restrict__ total)
{
    __shared__ int sums[256];
    int b = blockIdx.x;
    int tid = threadIdx.x;

    int vals[WPT];
    int s = 0;
    #pragma unroll
    for (int k = 0; k < WPT; k++) {
        int w = tid * WPT + k;
        vals[k] = (w < NWG) ? H[w * NB + b] : 0;
        s += vals[k];
    }
    sums[tid] = s;
    __syncthreads();
    for (int off = 1; off < 256; off <<= 1) {
        int t = (tid >= off) ? sums[tid - off] : 0;
        __syncthreads();
        sums[tid] += t;
        __syncthreads();
    }
    int run = sums[tid] - s;
    #pragma unroll
    for (int k = 0; k < WPT; k++) {
        int w = tid * WPT + k;
        if (w < NWG) H[w * NB + b] = run;
        run += vals[k];
    }
    if (tid == 255) total[b] = sums[255];
}

// Kernel C: exclusive scan of 128 bucket totals -> base.
__global__ __launch_bounds__(128) void scan_base_kernel(const int* __restrict__ total,
                                                        int* __restrict__ base)
{
    __shared__ int v[NB];
    int tid = threadIdx.x;
    int orig = total[tid];
    v[tid] = orig;
    __syncthreads();
    for (int off = 1; off < NB; off <<= 1) {
        int t = (tid >= off) ? v[tid - off] : 0;
        __syncthreads();
        v[tid] += t;
        __syncthreads();
    }
    base[tid] = v[tid] - orig;
}

// ---------------------------------------------------------------------------
// Fused msg-compute + scatter, fp16 g8 gather (16 B/edge random footprint).
// ---------------------------------------------------------------------------
__device__ __forceinline__ float msg_dot(uint4 gu, f4 a0, f4 a1, float base) {
    union { uint4 u; _Float16 h[8]; } pk; pk.u = gu;
    float m = base;
    m = fmaf((float)pk.h[0], a0[0], m);
    m = fmaf((float)pk.h[1], a0[1], m);
    m = fmaf((float)pk.h[2], a0[2], m);
    m = fmaf((float)pk.h[3], a0[3], m);
    m = fmaf((float)pk.h[4], a1[0], m);
    m = fmaf((float)pk.h[5], a1[1], m);
    m = fmaf((float)pk.h[6], a1[2], m);
    m = fmaf((float)pk.h[7], a1[3], m);
    return m;
}

__device__ __forceinline__ void compute_msgs8(
    int tid, int ebase,
    const int* __restrict__ src, const int* __restrict__ dst,
    const float* __restrict__ ea, const uint4* __restrict__ g8,
    const _Float16* __restrict__ gc,
    int* dloc, float* mloc)
{
    int sl[ITERS];
    #pragma unroll
    for (int it = 0; it < ITERS; ++it) {
        int e = ebase + it * 256 + tid;
        sl[it] = __builtin_nontemporal_load(&src[e]);
        dloc[it] = __builtin_nontemporal_load(&dst[e]);
    }
    #pragma unroll
    for (int h = 0; h < 2; ++h) {
        uint4 g[4]; f4 a0[4], a1[4];
        float gv[4];
        #pragma unroll
        for (int k = 0; k < 4; ++k) {
            int it = h * 4 + k;
            int e = ebase + it * 256 + tid;
            int s = sl[it];
            g[k] = g8[s];
            gv[k] = (float)gc[s];
            const f4* ap = (const f4*)(ea + (size_t)e * 8);
            a0[k] = __builtin_nontemporal_load(ap);
            a1[k] = __builtin_nontemporal_load(ap + 1);
        }
        #pragma unroll
        for (int k = 0; k < 4; ++k)
            mloc[h * 4 + k] = msg_dot(g[k], a0[k], a1[k], gv[k]);
    }
}

__global__ __launch_bounds__(256) void scatter_fused_kernel(
    const int* __restrict__ src1, const int* __restrict__ dst1,
    const float* __restrict__ ea1, const uint4* __restrict__ g8_1, const _Float16* __restrict__ gc_1,
    const int* __restrict__ src2, const int* __restrict__ dst2,
    const float* __restrict__ ea2, const uint4* __restrict__ g8_2, const _Float16* __restrict__ gc_2,
    const int* __restrict__ H, const int* __restrict__ base,
    float* __restrict__ msgs_out, unsigned short* __restrict__ lidx_out)
{
    __shared__ int cnt[NB];              // counts, then cursors
    __shared__ int sv[NB];               // scan scratch
    __shared__ int gbase[NB];            // global dest base minus local offset
    __shared__ unsigned int lu[CHUNK];   // packed (bucket<<12 | lidx)
    __shared__ float lm[CHUNK];          // staged msgs

    int tid = threadIdx.x;
    if (tid < NB) cnt[tid] = 0;
    __syncthreads();

    int cbase = blockIdx.x * CHUNK;
    int dloc[ITERS];
    float mloc[ITERS];

    if (cbase + CHUNK <= E1) {
        compute_msgs8(tid, cbase, src1, dst1, ea1, g8_1, gc_1, dloc, mloc);
    } else if (cbase >= E1 && cbase + CHUNK <= TOTAL_E) {
        compute_msgs8(tid, cbase - E1, src2, dst2, ea2, g8_2, gc_2, dloc, mloc);
    } else {
        // straddling (WG 976) or partial-tail (WG 1953) chunk: generic path
        #pragma unroll
        for (int it = 0; it < ITERS; ++it) {
            int t = cbase + it * 256 + tid;
            int d = -1; float m = 0.f;
            if (t < TOTAL_E) {
                const int* srcp; const int* dstp; const float* eap;
                const uint4* g8p; const _Float16* gcp; int e;
                if (t < E1) { e = t;      srcp = src1; dstp = dst1; eap = ea1; g8p = g8_1; gcp = gc_1; }
                else        { e = t - E1; srcp = src2; dstp = dst2; eap = ea2; g8p = g8_2; gcp = gc_2; }
                int s = srcp[e];
                d = dstp[e];
                uint4 gu = g8p[s];
                const f4* ap = (const f4*)(eap + (size_t)e * 8);
                f4 a0 = ap[0];
                f4 a1 = ap[1];
                m = msg_dot(gu, a0, a1, (float)gcp[s]);
            }
            dloc[it] = d; mloc[it] = m;
        }
    }

    // local histogram
    #pragma unroll
    for (int it = 0; it < ITERS; ++it)
        if (dloc[it] >= 0) atomicAdd(&cnt[dloc[it] >> BSHIFT], 1);
    __syncthreads();

    // exclusive scan of cnt -> local offsets; build gbase; reset cursors
    int myc = 0;
    if (tid < NB) { myc = cnt[tid]; sv[tid] = myc; }
    __syncthreads();
    for (int off = 1; off < NB; off <<= 1) {
        int t = (tid < NB && tid >= off) ? sv[tid - off] : 0;
        __syncthreads();
        if (tid < NB) sv[tid] += t;
        __syncthreads();
    }
    if (tid < NB) {
        int loff = sv[tid] - myc;
        gbase[tid] = H[blockIdx.x * NB + tid] + base[tid] - loff;
        cnt[tid] = loff;             // cursor starts at local offset
    }
    __syncthreads();

    // placement: stage into LDS in bucket-sorted order
    #pragma unroll
    for (int it = 0; it < ITERS; ++it) {
        int d = dloc[it];
        if (d >= 0) {
            int b = d >> BSHIFT;
            int slot = atomicAdd(&cnt[b], 1);
            lu[slot] = ((unsigned)b << BSHIFT) | (unsigned)(d & 4095);
            lm[slot] = mloc[it];
        }
    }
    __syncthreads();

    // coalesced flush: consecutive slots in a bucket -> consecutive global addrs
    int nvalid = TOTAL_E - cbase;
    if (nvalid > CHUNK) nvalid = CHUNK;
    for (int i = tid; i < nvalid; i += 256) {
        unsigned u = lu[i];
        int b = (int)(u >> BSHIFT);
        int g = gbase[b] + i;
        __builtin_nontemporal_store(lm[i], &msgs_out[g]);
        __builtin_nontemporal_store((unsigned short)(u & 4095u), &lidx_out[g]);
    }
}

// ---------------------------------------------------------------------------
// Kernel F: per-bucket LDS accumulate (4096 fp32), bucket split over 4 WGs;
// partials written as plain coalesced stores (NO global atomics -- R4 lesson).
// ---------------------------------------------------------------------------
__global__ __launch_bounds__(512) void reduce_kernel(
    const float* __restrict__ msgs, const unsigned short* __restrict__ lidx,
    const int* __restrict__ base, const int* __restrict__ total,
    float* __restrict__ part)
{
    __shared__ float acc[4096];
    for (int i = threadIdx.x; i < 4096; i += 512) acc[i] = 0.f;
    __syncthreads();

    int b = blockIdx.x >> 2;
    int k = blockIdx.x & 3;
    int start = base[b];
    int cnt = total[b];
    int q = (cnt + 3) >> 2;
    int s0 = k * q;
    int s1 = s0 + q; if (s1 > cnt) s1 = cnt;

    for (int i = s0 + threadIdx.x; i < s1; i += 512) {
        unsigned short li = __builtin_nontemporal_load(&lidx[start + i]);
        float mv = __builtin_nontemporal_load(&msgs[start + i]);
        atomicAdd(&acc[li], mv);
    }
    __syncthreads();

    float* dp = part + (size_t)blockIdx.x * 4096;
    for (int i = threadIdx.x; i < 4096; i += 512)
        __builtin_nontemporal_store(acc[i], &dp[i]);
}

// Kernel G: out[n] += sum of the 4 partials for n's bucket (root already there).
__global__ __launch_bounds__(256) void merge_kernel(
    const float* __restrict__ part, float* __restrict__ out)
{
    int n = blockIdx.x * 256 + threadIdx.x;
    if (n < N_I) {
        int b = n >> BSHIFT;
        int i = n & 4095;
        const float* p = part + (size_t)b * 4 * 4096 + i;
        out[n] += (p[0] + p[4096]) + (p[8192] + p[12288]);
    }
}

// ---------------------------------------------------------------------------
// Fallback: atomic edge kernel (used only if ws too small for the pipeline).
// ---------------------------------------------------------------------------
__global__ __launch_bounds__(256) void edge_kernel_atomic(
    const int* __restrict__ src1, const int* __restrict__ dst1,
    const float* __restrict__ ea1, const uint4* __restrict__ g8_1, const _Float16* __restrict__ gc_1,
    const int* __restrict__ src2, const int* __restrict__ dst2,
    const float* __restrict__ ea2, const uint4* __restrict__ g8_2, const _Float16* __restrict__ gc_2,
    float* __restrict__ out)
{
    int t = blockIdx.x * 256 + threadIdx.x;
    if (t >= TOTAL_E) return;
    const int* srcp; const int* dstp; const float* eap;
    const uint4* g8p; const _Float16* gcp; int e;
    if (t < E1) { e = t;      srcp = src1; dstp = dst1; eap = ea1; g8p = g8_1; gcp = gc_1; }
    else        { e = t - E1; srcp = src2; dstp = dst2; eap = ea2; g8p = g8_2; gcp = gc_2; }
    int s = srcp[e];
    int d = dstp[e];
    uint4 gu = g8p[s];
    const f4* ap = (const f4*)(eap + (size_t)e * 8);
    f4 a0 = ap[0];
    f4 a1 = ap[1];
    float m = msg_dot(gu, a0, a1, (float)gcp[s]);
    atomicAdd(out + d, m);
}

extern "C" void kernel_launch(void* const* d_in, const int* in_sizes, int n_in,
                              void* d_out, int out_size, void* d_ws, size_t ws_size,
                              hipStream_t stream) {
    const float* x_i  = (const float*)d_in[0];
    const float* x_h  = (const float*)d_in[1];
    const float* ea_h = (const float*)d_in[2];
    const float* ea_i = (const float*)d_in[3];
    const float* We_h = (const float*)d_in[4];
    const float* be_h = (const float*)d_in[5];
    const float* We_i = (const float*)d_in[6];
    const float* be_i = (const float*)d_in[7];
    const float* Wr_h = (const float*)d_in[8];
    const float* br_h = (const float*)d_in[9];
    const float* Wr_i = (const float*)d_in[10];
    const float* br_i = (const float*)d_in[11];
    const int* src_h = (const int*)d_in[12];
    const int* dst_h = (const int*)d_in[13];
    const int* src_i = (const int*)d_in[14];
    const int* dst_i = (const int*)d_in[15];

    float* out = (float*)d_out;

    // workspace layout (~37.8 MB total):
    //   g8_i [0, 8.0 MB), g8_h [8.0, 11.2 MB)   -- dead after scatter
    //   part [0, 8.06 MB) aliases g8 region      -- used in reduce/merge
    //   gc_i [11.2, 12.2 MB), gc_h [12.2, 12.6 MB)
    //   msgs [12.8, 28.8 MB) fp32
    //   lidx [28.8, 36.8 MB) u16
    //   H    [36.8, 37.8 MB), tot/bas after
    char* ws = (char*)d_ws;
    uint4*    g8_i = (uint4*)ws;                            //  8,000,000 B
    uint4*    g8_h = (uint4*)(ws + 8000000);                //  3,200,000 B
    _Float16* gc_i = (_Float16*)(ws + 11200000);            //  1,000,000 B
    _Float16* gc_h = (_Float16*)(ws + 12200000);            //    400,000 B
    float*    part = (float*)ws;                            //  8,060,928 B (aliases g8)
    float*    msgs = (float*)(ws + 12800000);               // 16,000,000 B
    unsigned short* lidx = (unsigned short*)(ws + 28800000);//  8,000,000 B
    int*      H    = (int*)(ws + 36800000);                 //  1,000,448 B
    int*      tot  = (int*)(ws + 37800448);                 //    512 B
    int*      bas  = (int*)(ws + 37800960);                 //    512 B
    const size_t WS_NEEDED = 37801472;                      // ~37.8 MB

    precompute_both<<<NBI_BLK + NBH_BLK, 256, 0, stream>>>(
        x_i, We_i, be_i, g8_i, gc_i,
        x_h, We_h, be_h, g8_h, gc_h,
        Wr_h, Wr_i, br_h, br_i, out);

    if (ws_size >= WS_NEEDED) {
        hist_kernel<<<NWG, 256, 0, stream>>>(dst_h, dst_i, H);
        scan_cols_kernel<<<NB, 256, 0, stream>>>(H, tot);
        scan_base_kernel<<<1, NB, 0, stream>>>(tot, bas);
        scatter_fused_kernel<<<NWG, 256, 0, stream>>>(
            src_h, dst_h, ea_h, g8_h, gc_h,
            src_i, dst_i, ea_i, g8_i, gc_i,
            H, bas, msgs, lidx);
        reduce_kernel<<<NBK * 4, 512, 0, stream>>>(msgs, lidx, bas, tot, part);
        merge_kernel<<<(N_I + 255) / 256, 256, 0, stream>>>(part, out);
    } else {
        edge_kernel_atomic<<<(TOTAL_E + 255) / 256, 256, 0, stream>>>(
            src_h, dst_h, ea_h, g8_h, gc_h,
            src_i, dst_i, ea_i, g8_i, gc_i, out);
    }
}

// Round 6
// 364.796 us; speedup vs baseline: 1.2103x; 1.0012x over previous
//
#include <hip/hip_runtime.h>

#define N_I 500000
#define N_H 200000
#define E1  2000000
#define E2  2000000
#define TOTAL_E (E1 + E2)

#define BSHIFT 12                   // bucket = dst >> 12 (4096 nodes/bucket)
#define NB 128                      // allocated buckets; 123 used
#define NBK ((N_I + 4095) / 4096)   // = 123 used buckets
#define BLK 512                     // threads per block (scatter/hist)
#define CHUNK 4096                  // edges per workgroup (hist/scatter)
#define NWG ((TOTAL_E + CHUNK - 1) / CHUNK)   // = 977
#define WPT 4                       // H entries per thread in scan_cols (256*4=1024>=977)
#define ITERS (CHUNK / BLK)         // 8 edges per thread

#define NBI_BLK ((N_I + BLK - 1) / BLK)   // 977
#define NBH_BLK ((N_H + BLK - 1) / BLK)   // 391

typedef float f4 __attribute__((ext_vector_type(4)));   // nontemporal-compatible

// ---------------------------------------------------------------------------
// Fused setup kernel, 3-way blockIdx partition:
//   [0, NBI_BLK)                : precompute g8/gc for indivi + root -> out
//   [NBI_BLK, NBI_BLK+NBH_BLK)  : precompute g8/gc for house
//   [.., +NWG)                  : dst histogram (independent; overlaps)
// g8[n] = 8 x fp16 of x[n]^T @ W_edge (16 B, gathered per edge)
// gc[n] = fp16 dot(x[n], b_edge)      (2 B, L2-resident)
// ---------------------------------------------------------------------------
template<int F, bool ROOT>
__device__ __forceinline__ void precompute_body(
    int blk, int tid,
    const float* __restrict__ x, const float* __restrict__ W, const float* __restrict__ b,
    uint4* __restrict__ g8, _Float16* __restrict__ gc, int n,
    const float* __restrict__ rW1, const float* __restrict__ rW2,
    const float* __restrict__ rb1, const float* __restrict__ rb2,
    float* __restrict__ out,
    float* Wf, float* bv, float* wr)
{
    for (int i = tid; i < F * 8; i += BLK) Wf[i] = W[i];
    if (tid < F) {
        bv[tid] = b[tid];
        if (ROOT) wr[tid] = rW1[tid] + rW2[tid];
    }
    __syncthreads();

    int nid = blk * BLK + tid;
    if (nid >= n) return;

    float xv[F];
    const f4* xp = (const f4*)(x + (size_t)nid * F);
    #pragma unroll
    for (int q = 0; q < F / 4; q++) {
        f4 v = __builtin_nontemporal_load(xp + q);
        xv[q*4+0] = v[0]; xv[q*4+1] = v[1]; xv[q*4+2] = v[2]; xv[q*4+3] = v[3];
    }

    float acc[9];
    #pragma unroll
    for (int k = 0; k < 9; k++) acc[k] = 0.f;

    #pragma unroll
    for (int j = 0; j < F; j++) {
        float4 w0 = *(const float4*)(Wf + j * 8);
        float4 w1 = *(const float4*)(Wf + j * 8 + 4);
        float xj = xv[j];
        acc[0] = fmaf(xj, w0.x, acc[0]);
        acc[1] = fmaf(xj, w0.y, acc[1]);
        acc[2] = fmaf(xj, w0.z, acc[2]);
        acc[3] = fmaf(xj, w0.w, acc[3]);
        acc[4] = fmaf(xj, w1.x, acc[4]);
        acc[5] = fmaf(xj, w1.y, acc[5]);
        acc[6] = fmaf(xj, w1.z, acc[6]);
        acc[7] = fmaf(xj, w1.w, acc[7]);
        acc[8] = fmaf(xj, bv[j], acc[8]);
    }

    union { _Float16 h[8]; uint4 u; } pk;
    #pragma unroll
    for (int k = 0; k < 8; k++) pk.h[k] = (_Float16)acc[k];
    g8[nid] = pk.u;
    gc[nid] = (_Float16)acc[8];

    if (ROOT) {
        float r = rb1[0] + rb2[0];
        #pragma unroll
        for (int j = 0; j < F; j++) r = fmaf(xv[j], wr[j], r);
        out[nid] = r;
    }
}

__global__ __launch_bounds__(BLK) void setup_kernel(
    const float* __restrict__ x_i, const float* __restrict__ We_i, const float* __restrict__ be_i,
    uint4* __restrict__ g8_i, _Float16* __restrict__ gc_i,
    const float* __restrict__ x_h, const float* __restrict__ We_h, const float* __restrict__ be_h,
    uint4* __restrict__ g8_h, _Float16* __restrict__ gc_h,
    const float* __restrict__ rW1, const float* __restrict__ rW2,
    const float* __restrict__ rb1, const float* __restrict__ rb2,
    float* __restrict__ out,
    const int* __restrict__ dst1, const int* __restrict__ dst2,
    int* __restrict__ H)
{
    __shared__ float Wf[32 * 8];
    __shared__ float bv[32];
    __shared__ float wr[32];
    __shared__ int hist[NB];

    int bid = blockIdx.x;
    int tid = threadIdx.x;

    if (bid < NBI_BLK) {
        precompute_body<32, true>(bid, tid, x_i, We_i, be_i,
                                  g8_i, gc_i, N_I, rW1, rW2, rb1, rb2, out, Wf, bv, wr);
    } else if (bid < NBI_BLK + NBH_BLK) {
        precompute_body<16, false>(bid - NBI_BLK, tid, x_h, We_h, be_h,
                                   g8_h, gc_h, N_H, nullptr, nullptr, nullptr, nullptr,
                                   nullptr, Wf, bv, wr);
    } else {
        int blk = bid - NBI_BLK - NBH_BLK;
        if (tid < NB) hist[tid] = 0;
        __syncthreads();
        int base = blk * CHUNK;
        #pragma unroll
        for (int it = 0; it < ITERS; ++it) {
            int t = base + it * BLK + tid;
            if (t < TOTAL_E) {
                int d = (t < E1) ? __builtin_nontemporal_load(&dst1[t])
                                 : __builtin_nontemporal_load(&dst2[t - E1]);
                atomicAdd(&hist[d >> BSHIFT], 1);
            }
        }
        __syncthreads();
        if (tid < NB) H[blk * NB + tid] = hist[tid];
    }
}

// Kernel B: per bucket b, exclusive scan of H[w][b] over w, in place.
__global__ __launch_bounds__(256) void scan_cols_kernel(int* __restrict__ H,
                                                        int* __restrict__ total)
{
    __shared__ int sums[256];
    int b = blockIdx.x;
    int tid = threadIdx.x;

    int vals[WPT];
    int s = 0;
    #pragma unroll
    for (int k = 0; k < WPT; k++) {
        int w = tid * WPT + k;
        vals[k] = (w < NWG) ? H[w * NB + b] : 0;
        s += vals[k];
    }
    sums[tid] = s;
    __syncthreads();
    for (int off = 1; off < 256; off <<= 1) {
        int t = (tid >= off) ? sums[tid - off] : 0;
        __syncthreads();
        sums[tid] += t;
        __syncthreads();
    }
    int run = sums[tid] - s;
    #pragma unroll
    for (int k = 0; k < WPT; k++) {
        int w = tid * WPT + k;
        if (w < NWG) H[w * NB + b] = run;
        run += vals[k];
    }
    if (tid == 255) total[b] = sums[255];
}

// Kernel C: exclusive scan of 128 bucket totals -> base.
__global__ __launch_bounds__(128) void scan_base_kernel(const int* __restrict__ total,
                                                        int* __restrict__ base)
{
    __shared__ int v[NB];
    int tid = threadIdx.x;
    int orig = total[tid];
    v[tid] = orig;
    __syncthreads();
    for (int off = 1; off < NB; off <<= 1) {
        int t = (tid >= off) ? v[tid - off] : 0;
        __syncthreads();
        v[tid] += t;
        __syncthreads();
    }
    base[tid] = v[tid] - orig;
}

// ---------------------------------------------------------------------------
// Fused msg-compute + scatter, fp16 g8 gather (16 B/edge random footprint).
// CHUNK=4096 x 512 threads: half the scan/barrier phases of the 2048 version,
// ~32-pair coalesced flush runs per bucket.
// ---------------------------------------------------------------------------
__device__ __forceinline__ float msg_dot(uint4 gu, f4 a0, f4 a1, float base) {
    union { uint4 u; _Float16 h[8]; } pk; pk.u = gu;
    float m = base;
    m = fmaf((float)pk.h[0], a0[0], m);
    m = fmaf((float)pk.h[1], a0[1], m);
    m = fmaf((float)pk.h[2], a0[2], m);
    m = fmaf((float)pk.h[3], a0[3], m);
    m = fmaf((float)pk.h[4], a1[0], m);
    m = fmaf((float)pk.h[5], a1[1], m);
    m = fmaf((float)pk.h[6], a1[2], m);
    m = fmaf((float)pk.h[7], a1[3], m);
    return m;
}

__device__ __forceinline__ void compute_msgs8(
    int tid, int ebase,
    const int* __restrict__ src, const int* __restrict__ dst,
    const float* __restrict__ ea, const uint4* __restrict__ g8,
    const _Float16* __restrict__ gc,
    int* dloc, float* mloc)
{
    int sl[ITERS];
    #pragma unroll
    for (int it = 0; it < ITERS; ++it) {
        int e = ebase + it * BLK + tid;
        sl[it] = __builtin_nontemporal_load(&src[e]);
        dloc[it] = __builtin_nontemporal_load(&dst[e]);
    }
    #pragma unroll
    for (int h = 0; h < 2; ++h) {
        uint4 g[4]; f4 a0[4], a1[4];
        float gv[4];
        #pragma unroll
        for (int k = 0; k < 4; ++k) {
            int it = h * 4 + k;
            int e = ebase + it * BLK + tid;
            int s = sl[it];
            g[k] = g8[s];
            gv[k] = (float)gc[s];
            const f4* ap = (const f4*)(ea + (size_t)e * 8);
            a0[k] = __builtin_nontemporal_load(ap);
            a1[k] = __builtin_nontemporal_load(ap + 1);
        }
        #pragma unroll
        for (int k = 0; k < 4; ++k)
            mloc[h * 4 + k] = msg_dot(g[k], a0[k], a1[k], gv[k]);
    }
}

__global__ __launch_bounds__(BLK) void scatter_fused_kernel(
    const int* __restrict__ src1, const int* __restrict__ dst1,
    const float* __restrict__ ea1, const uint4* __restrict__ g8_1, const _Float16* __restrict__ gc_1,
    const int* __restrict__ src2, const int* __restrict__ dst2,
    const float* __restrict__ ea2, const uint4* __restrict__ g8_2, const _Float16* __restrict__ gc_2,
    const int* __restrict__ H, const int* __restrict__ base,
    float* __restrict__ msgs_out, unsigned short* __restrict__ lidx_out)
{
    __shared__ int cnt[NB];              // counts, then cursors
    __shared__ int sv[NB];               // scan scratch
    __shared__ int gbase[NB];            // global dest base minus local offset
    __shared__ unsigned int lu[CHUNK];   // packed (bucket<<12 | lidx)
    __shared__ float lm[CHUNK];          // staged msgs

    int tid = threadIdx.x;
    if (tid < NB) cnt[tid] = 0;
    __syncthreads();

    int cbase = blockIdx.x * CHUNK;
    int dloc[ITERS];
    float mloc[ITERS];

    if (cbase + CHUNK <= E1) {
        compute_msgs8(tid, cbase, src1, dst1, ea1, g8_1, gc_1, dloc, mloc);
    } else if (cbase >= E1 && cbase + CHUNK <= TOTAL_E) {
        compute_msgs8(tid, cbase - E1, src2, dst2, ea2, g8_2, gc_2, dloc, mloc);
    } else {
        // straddling (WG 488) or partial-tail (WG 976) chunk: generic path
        #pragma unroll
        for (int it = 0; it < ITERS; ++it) {
            int t = cbase + it * BLK + tid;
            int d = -1; float m = 0.f;
            if (t < TOTAL_E) {
                const int* srcp; const int* dstp; const float* eap;
                const uint4* g8p; const _Float16* gcp; int e;
                if (t < E1) { e = t;      srcp = src1; dstp = dst1; eap = ea1; g8p = g8_1; gcp = gc_1; }
                else        { e = t - E1; srcp = src2; dstp = dst2; eap = ea2; g8p = g8_2; gcp = gc_2; }
                int s = srcp[e];
                d = dstp[e];
                uint4 gu = g8p[s];
                const f4* ap = (const f4*)(eap + (size_t)e * 8);
                f4 a0 = ap[0];
                f4 a1 = ap[1];
                m = msg_dot(gu, a0, a1, (float)gcp[s]);
            }
            dloc[it] = d; mloc[it] = m;
        }
    }

    // local histogram
    #pragma unroll
    for (int it = 0; it < ITERS; ++it)
        if (dloc[it] >= 0) atomicAdd(&cnt[dloc[it] >> BSHIFT], 1);
    __syncthreads();

    // exclusive scan of cnt -> local offsets; build gbase; reset cursors
    int myc = 0;
    if (tid < NB) { myc = cnt[tid]; sv[tid] = myc; }
    __syncthreads();
    for (int off = 1; off < NB; off <<= 1) {
        int t = (tid < NB && tid >= off) ? sv[tid - off] : 0;
        __syncthreads();
        if (tid < NB) sv[tid] += t;
        __syncthreads();
    }
    if (tid < NB) {
        int loff = sv[tid] - myc;
        gbase[tid] = H[blockIdx.x * NB + tid] + base[tid] - loff;
        cnt[tid] = loff;             // cursor starts at local offset
    }
    __syncthreads();

    // placement: stage into LDS in bucket-sorted order
    #pragma unroll
    for (int it = 0; it < ITERS; ++it) {
        int d = dloc[it];
        if (d >= 0) {
            int b = d >> BSHIFT;
            int slot = atomicAdd(&cnt[b], 1);
            lu[slot] = ((unsigned)b << BSHIFT) | (unsigned)(d & 4095);
            lm[slot] = mloc[it];
        }
    }
    __syncthreads();

    // coalesced flush: consecutive slots in a bucket -> consecutive global addrs
    int nvalid = TOTAL_E - cbase;
    if (nvalid > CHUNK) nvalid = CHUNK;
    for (int i = tid; i < nvalid; i += BLK) {
        unsigned u = lu[i];
        int b = (int)(u >> BSHIFT);
        int g = gbase[b] + i;
        __builtin_nontemporal_store(lm[i], &msgs_out[g]);
        __builtin_nontemporal_store((unsigned short)(u & 4095u), &lidx_out[g]);
    }
}

// ---------------------------------------------------------------------------
// Kernel F: per-bucket LDS accumulate (4096 fp32), bucket split over 4 WGs;
// partials written as plain coalesced stores (NO global atomics -- R4 lesson).
// ---------------------------------------------------------------------------
__global__ __launch_bounds__(512) void reduce_kernel(
    const float* __restrict__ msgs, const unsigned short* __restrict__ lidx,
    const int* __restrict__ base, const int* __restrict__ total,
    float* __restrict__ part)
{
    __shared__ float acc[4096];
    for (int i = threadIdx.x; i < 4096; i += 512) acc[i] = 0.f;
    __syncthreads();

    int b = blockIdx.x >> 2;
    int k = blockIdx.x & 3;
    int start = base[b];
    int cnt = total[b];
    int q = (cnt + 3) >> 2;
    int s0 = k * q;
    int s1 = s0 + q; if (s1 > cnt) s1 = cnt;

    for (int i = s0 + threadIdx.x; i < s1; i += 512) {
        unsigned short li = __builtin_nontemporal_load(&lidx[start + i]);
        float mv = __builtin_nontemporal_load(&msgs[start + i]);
        atomicAdd(&acc[li], mv);
    }
    __syncthreads();

    float* dp = part + (size_t)blockIdx.x * 4096;
    for (int i = threadIdx.x; i < 4096; i += 512)
        __builtin_nontemporal_store(acc[i], &dp[i]);
}

// Kernel G: out[n] += sum of the 4 partials for n's bucket (root already there).
__global__ __launch_bounds__(256) void merge_kernel(
    const float* __restrict__ part, float* __restrict__ out)
{
    int n = blockIdx.x * 256 + threadIdx.x;
    if (n < N_I) {
        int b = n >> BSHIFT;
        int i = n & 4095;
        const float* p = part + (size_t)b * 4 * 4096 + i;
        out[n] += (p[0] + p[4096]) + (p[8192] + p[12288]);
    }
}

// ---------------------------------------------------------------------------
// Fallback: atomic edge kernel (used only if ws too small for the pipeline).
// ---------------------------------------------------------------------------
__global__ __launch_bounds__(256) void edge_kernel_atomic(
    const int* __restrict__ src1, const int* __restrict__ dst1,
    const float* __restrict__ ea1, const uint4* __restrict__ g8_1, const _Float16* __restrict__ gc_1,
    const int* __restrict__ src2, const int* __restrict__ dst2,
    const float* __restrict__ ea2, const uint4* __restrict__ g8_2, const _Float16* __restrict__ gc_2,
    float* __restrict__ out)
{
    int t = blockIdx.x * 256 + threadIdx.x;
    if (t >= TOTAL_E) return;
    const int* srcp; const int* dstp; const float* eap;
    const uint4* g8p; const _Float16* gcp; int e;
    if (t < E1) { e = t;      srcp = src1; dstp = dst1; eap = ea1; g8p = g8_1; gcp = gc_1; }
    else        { e = t - E1; srcp = src2; dstp = dst2; eap = ea2; g8p = g8_2; gcp = gc_2; }
    int s = srcp[e];
    int d = dstp[e];
    uint4 gu = g8p[s];
    const f4* ap = (const f4*)(eap + (size_t)e * 8);
    f4 a0 = ap[0];
    f4 a1 = ap[1];
    float m = msg_dot(gu, a0, a1, (float)gcp[s]);
    atomicAdd(out + d, m);
}

extern "C" void kernel_launch(void* const* d_in, const int* in_sizes, int n_in,
                              void* d_out, int out_size, void* d_ws, size_t ws_size,
                              hipStream_t stream) {
    const float* x_i  = (const float*)d_in[0];
    const float* x_h  = (const float*)d_in[1];
    const float* ea_h = (const float*)d_in[2];
    const float* ea_i = (const float*)d_in[3];
    const float* We_h = (const float*)d_in[4];
    const float* be_h = (const float*)d_in[5];
    const float* We_i = (const float*)d_in[6];
    const float* be_i = (const float*)d_in[7];
    const float* Wr_h = (const float*)d_in[8];
    const float* br_h = (const float*)d_in[9];
    const float* Wr_i = (const float*)d_in[10];
    const float* br_i = (const float*)d_in[11];
    const int* src_h = (const int*)d_in[12];
    const int* dst_h = (const int*)d_in[13];
    const int* src_i = (const int*)d_in[14];
    const int* dst_i = (const int*)d_in[15];

    float* out = (float*)d_out;

    // workspace layout (~37.3 MB total):
    //   g8_i [0, 8.0 MB), g8_h [8.0, 11.2 MB)   -- dead after scatter
    //   part [0, 8.06 MB) aliases g8 region      -- used in reduce/merge
    //   gc_i [11.2, 12.2 MB), gc_h [12.2, 12.6 MB)
    //   msgs [12.8, 28.8 MB) fp32
    //   lidx [28.8, 36.8 MB) u16
    //   H    [36.8, 37.3 MB) (977*128*4), tot/bas after
    char* ws = (char*)d_ws;
    uint4*    g8_i = (uint4*)ws;                            //  8,000,000 B
    uint4*    g8_h = (uint4*)(ws + 8000000);                //  3,200,000 B
    _Float16* gc_i = (_Float16*)(ws + 11200000);            //  1,000,000 B
    _Float16* gc_h = (_Float16*)(ws + 12200000);            //    400,000 B
    float*    part = (float*)ws;                            //  8,060,928 B (aliases g8)
    float*    msgs = (float*)(ws + 12800000);               // 16,000,000 B
    unsigned short* lidx = (unsigned short*)(ws + 28800000);//  8,000,000 B
    int*      H    = (int*)(ws + 36800000);                 //    500,224 B
    int*      tot  = (int*)(ws + 37300480);                 //    512 B
    int*      bas  = (int*)(ws + 37300992);                 //    512 B
    const size_t WS_NEEDED = 37301504;                      // ~37.3 MB

    if (ws_size >= WS_NEEDED) {
        setup_kernel<<<NBI_BLK + NBH_BLK + NWG, BLK, 0, stream>>>(
            x_i, We_i, be_i, g8_i, gc_i,
            x_h, We_h, be_h, g8_h, gc_h,
            Wr_h, Wr_i, br_h, br_i, out,
            dst_h, dst_i, H);
        scan_cols_kernel<<<NB, 256, 0, stream>>>(H, tot);
        scan_base_kernel<<<1, NB, 0, stream>>>(tot, bas);
        scatter_fused_kernel<<<NWG, BLK, 0, stream>>>(
            src_h, dst_h, ea_h, g8_h, gc_h,
            src_i, dst_i, ea_i, g8_i, gc_i,
            H, bas, msgs, lidx);
        reduce_kernel<<<NBK * 4, 512, 0, stream>>>(msgs, lidx, bas, tot, part);
        merge_kernel<<<(N_I + 255) / 256, 256, 0, stream>>>(part, out);
    } else {
        setup_kernel<<<NBI_BLK + NBH_BLK, BLK, 0, stream>>>(
            x_i, We_i, be_i, g8_i, gc_i,
            x_h, We_h, be_h, g8_h, gc_h,
            Wr_h, Wr_i, br_h, br_i, out,
            dst_h, dst_i, (int*)ws);   // hist partition absent (grid excludes it)
        edge_kernel_atomic<<<(TOTAL_E + 255) / 256, 256, 0, stream>>>(
            src_h, dst_h, ea_h, g8_h, gc_h,
            src_i, dst_i, ea_i, g8_i, gc_i, out);
    }
}